// Round 11
// baseline (1632.289 us; speedup 1.0000x reference)
//
#include <hip/hip_runtime.h>

#define BB 128
#define TT 2048
#define HH 64

__device__ __forceinline__ float sigm(float v) {
    return __builtin_amdgcn_rcpf(1.0f + __expf(-v));
}
__device__ __forceinline__ float ftanh(float v) {
    float e = __expf(-2.0f * fabsf(v));
    float r = (1.0f - e) * __builtin_amdgcn_rcpf(1.0f + e);
    return copysignf(r, v);
}

#define PIN4(v) asm volatile("" : "+v"((v).x), "+v"((v).y), "+v"((v).z), "+v"((v).w))
#define PINF(v) asm volatile("" : "+v"(v))
// dot of one float4 weight with one float4 h-slice
#define D4(W, H) ((W).x*(H).x + (W).y*(H).y + (W).z*(H).z + (W).w*(H).w)

// One block per batch, 12 waves. Lane (4g+q) of stage-wave (s,sw) owns
// gate-rows {d, 64+d, 128+d} (d = sw*16+g) x cols [16q,16q+16) = 48 floats
// in named float4 scalars w0..w11.
//
// R11 CHANGE vs R10: the liveness pins execute INSIDE the loop, every
// iteration. R2-R10 pinned only before the loop: that forces the value to
// exist at the pin, but in-loop uses of pure __restrict__ loads may still be
// REMATERIALIZED (re-loaded from L2) at each use -- which is why VGPR_Count
// always collapsed to the working set (48) and every structure paid a
// ~147KB/block/iter L2 stream (~1.6-2.4ms flat). An in-loop "+v" asm
// redefines the value each trip, so the next iteration MUST read the asm's
// output register: remat becomes illegal, loads hoist out, weights stay
// resident. The pins emit zero instructions.
//
// K-quarter partials combine via __shfl_xor(1),(2) in-wave; ONE barrier/iter.
//   s=0: h1(i)  = GRU1(h1(i-1), x(i))          [h1b parity]
//   s=1: xg(i-1)= Wih1*h1(i-1)+bih1            [xgb parity]
//   s=2: h2(i-2)= GRU2(h2(i-3), xg(i-2))       [h2b parity, ring store]
// fc head: wave 7 flushes 64 outputs every 64 iters from the 128-slot ring.
__global__ __launch_bounds__(768, 1)
void gru_fused(const float* __restrict__ x,
               const float* __restrict__ Wih0, const float* __restrict__ Whh0,
               const float* __restrict__ bih0, const float* __restrict__ bhh0,
               const float* __restrict__ Wih1, const float* __restrict__ Whh1,
               const float* __restrict__ bih1, const float* __restrict__ bhh1,
               const float* __restrict__ fcw, const float* __restrict__ fcb,
               float* __restrict__ out)
{
    const int t  = threadIdx.x;
    const int w  = t >> 6;          // wave 0..11
    const int j  = t & 63;          // lane
    const int s  = w >> 2;          // stage 0..2
    const int sw = w & 3;           // dim block
    const int g  = j >> 2;          // local dim 0..15
    const int q  = j & 3;           // K-quarter
    const int d  = sw * 16 + g;     // dim 0..63
    const int b  = blockIdx.x;

    __shared__ __align__(16) float xs[TT * 2];       // 16 KB input
    __shared__ __align__(16) float h1b[2][HH];       // parity
    __shared__ __align__(16) float h2b[2][HH];       // parity
    __shared__ __align__(16) float xgb[2][3 * HH];   // parity
    __shared__ __align__(16) float fwS[HH];
    __shared__ float ring[128][65];                  // h2 history, stride 65

    // ---- 48 weight floats: 3 rows x 16 cols, NAMED scalars ----
    const float* Wm = (s == 0) ? Whh0 : (s == 1) ? Wih1 : Whh1;
    const float4* p0 = (const float4*)(Wm + (size_t)(0 * HH + d) * HH + q * 16);
    const float4* p1 = (const float4*)(Wm + (size_t)(1 * HH + d) * HH + q * 16);
    const float4* p2 = (const float4*)(Wm + (size_t)(2 * HH + d) * HH + q * 16);
    float4 w0 = p0[0], w1 = p0[1], w2  = p0[2], w3  = p0[3];
    float4 w4 = p1[0], w5 = p1[1], w6  = p1[2], w7  = p1[3];
    float4 w8 = p2[0], w9 = p2[1], w10 = p2[2], w11 = p2[3];

    // biases (added AFTER the shfl combine, so loaded once per lane)
    float kb0, kb1, kb2, bi2 = 0.f;
    if (s == 0) {            // r,z: fold bih0+bhh0; n: bhh0 inside r*(), bih0 outside
        kb0 = bhh0[d] + bih0[d];
        kb1 = bhh0[HH + d] + bih0[HH + d];
        kb2 = bhh0[2 * HH + d];
        bi2 = bih0[2 * HH + d];
    } else if (s == 1) {
        kb0 = bih1[d]; kb1 = bih1[HH + d]; kb2 = bih1[2 * HH + d];
    } else {
        kb0 = bhh1[d]; kb1 = bhh1[HH + d]; kb2 = bhh1[2 * HH + d];
    }
    float wi0 = 0, wi1 = 0, wi2 = 0, wi3 = 0, wi4 = 0, wi5 = 0;
    if (s == 0) {
        wi0 = Wih0[d * 2];            wi1 = Wih0[d * 2 + 1];
        wi2 = Wih0[(HH + d) * 2];     wi3 = Wih0[(HH + d) * 2 + 1];
        wi4 = Wih0[(2 * HH + d) * 2]; wi5 = Wih0[(2 * HH + d) * 2 + 1];
    }
    const float fcbv = fcb[0];

    // ---- preload x, zero state ----
    {
        const float4* xp  = (const float4*)(x + (size_t)b * TT * 2);
        float4*       xsp = (float4*)xs;
        for (int i2 = t; i2 < TT * 2 / 4; i2 += 768) xsp[i2] = xp[i2];
    }
    if (t < 2 * HH) { ((float*)h1b)[t] = 0.f; ((float*)h2b)[t] = 0.f; }
    if (t < HH) fwS[t] = fcw[t];

    float hreg = 0.f;   // s0: h1[d]; s2: h2[d] (tracked redundantly by 4 lanes)

    for (int i = 0; i < TT + 2; ++i) {
        // In-loop liveness pins: redefine the weight/bias registers every
        // iteration so rematerialization-by-reload is illegal (see header).
        PIN4(w0); PIN4(w1); PIN4(w2);  PIN4(w3);
        PIN4(w4); PIN4(w5); PIN4(w6);  PIN4(w7);
        PIN4(w8); PIN4(w9); PIN4(w10); PIN4(w11);
        PINF(kb0); PINF(kb1); PINF(kb2); PINF(bi2);
        PINF(wi0); PINF(wi1); PINF(wi2); PINF(wi3); PINF(wi4); PINF(wi5);

        __syncthreads();
        const bool act = (s == 0) ? (i < TT)
                       : (s == 1) ? (i >= 1 && i <= TT)
                                  : (i >= 2);
        if (act) {
            const float4* hp = (const float4*)((s < 2) ? h1b[(i - 1) & 1]
                                                       : h2b[(i - 1) & 1]) + q * 4;
            float4 hA = hp[0], hB = hp[1], hC = hp[2], hD = hp[3];
            float a0 = (D4(w0, hA) + D4(w1, hB)) + (D4(w2,  hC) + D4(w3,  hD));
            float a1 = (D4(w4, hA) + D4(w5, hB)) + (D4(w6,  hC) + D4(w7,  hD));
            float a2 = (D4(w8, hA) + D4(w9, hB)) + (D4(w10, hC) + D4(w11, hD));
            // combine K-quarters in-wave (lanes 4g..4g+3), then biases once
            a0 += __shfl_xor(a0, 1); a0 += __shfl_xor(a0, 2);
            a1 += __shfl_xor(a1, 1); a1 += __shfl_xor(a1, 2);
            a2 += __shfl_xor(a2, 1); a2 += __shfl_xor(a2, 2);
            a0 += kb0; a1 += kb1; a2 += kb2;

            if (s == 0) {                        // layer-1 gates, step i
                float x0 = xs[2 * i], x1 = xs[2 * i + 1];
                float rr = sigm (fmaf(wi0, x0, fmaf(wi1, x1, a0)));
                float zz = sigm (fmaf(wi2, x0, fmaf(wi3, x1, a1)));
                float nn = ftanh(fmaf(wi4, x0, fmaf(wi5, x1, bi2)) + rr * a2);
                hreg = (1.f - zz) * nn + zz * hreg;
                if (q == 0) h1b[i & 1][d] = hreg;
            } else if (s == 1) {                 // xg(i-1) producer
                if (q == 0) {
                    float* xg = xgb[(i - 1) & 1];
                    xg[d] = a0; xg[HH + d] = a1; xg[2 * HH + d] = a2;
                }
            } else {                             // layer-2 gates, step i-2
                const float* xg = xgb[(i - 2) & 1];
                float rr = sigm (xg[d]          + a0);
                float zz = sigm (xg[HH + d]     + a1);
                float nn = ftanh(xg[2 * HH + d] + rr * a2);
                hreg = (1.f - zz) * nn + zz * hreg;
                if (q == 0) {
                    h2b[i & 1][d] = hreg;
                    ring[(i - 2) & 127][d] = hreg;
                }
            }
        }
        // fc-head flush: wave 7, every 64 iters, 64 finished timesteps
        if (w == 7 && i >= 66 && ((i - 66) & 63) == 0) {
            const int tt = ((i - 66) >> 6) * 64 + j;
            const float* rr2 = ring[tt & 127];
            float acc0 = 0.f, acc1 = 0.f;
            #pragma unroll
            for (int k = 0; k < 64; k += 2) {
                acc0 += rr2[k]     * fwS[k];
                acc1 += rr2[k + 1] * fwS[k + 1];
            }
            out[(size_t)b * TT + tt] = acc0 + acc1 + fcbv;
        }
    }
    __syncthreads();
    if (w == 7) {                                // final chunk: t = 1984..2047
        const int tt = 31 * 64 + j;
        const float* rr2 = ring[tt & 127];
        float acc0 = 0.f, acc1 = 0.f;
        #pragma unroll
        for (int k = 0; k < 64; k += 2) {
            acc0 += rr2[k]     * fwS[k];
            acc1 += rr2[k + 1] * fwS[k + 1];
        }
        out[(size_t)b * TT + tt] = acc0 + acc1 + fcbv;
    }
}

extern "C" void kernel_launch(void* const* d_in, const int* in_sizes, int n_in,
                              void* d_out, int out_size, void* d_ws, size_t ws_size,
                              hipStream_t stream) {
    const float* x    = (const float*)d_in[0];
    const float* Wih0 = (const float*)d_in[1];
    const float* Whh0 = (const float*)d_in[2];
    const float* bih0 = (const float*)d_in[3];
    const float* bhh0 = (const float*)d_in[4];
    const float* Wih1 = (const float*)d_in[5];
    const float* Whh1 = (const float*)d_in[6];
    const float* bih1 = (const float*)d_in[7];
    const float* bhh1 = (const float*)d_in[8];
    const float* fcw  = (const float*)d_in[9];
    const float* fcb  = (const float*)d_in[10];
    float* out = (float*)d_out;

    gru_fused<<<BB, 768, 0, stream>>>(x, Wih0, Whh0, bih0, bhh0,
                                      Wih1, Whh1, bih1, bhh1, fcw, fcb, out);
}

// Round 12
// 1428.148 us; speedup vs baseline: 1.1429x; 1.1429x over previous
//
#include <hip/hip_runtime.h>

#define BB 128
#define TT 2048
#define HH 64

__device__ __forceinline__ float sigm(float v) {
    return __builtin_amdgcn_rcpf(1.0f + __expf(-v));
}
__device__ __forceinline__ float ftanh(float v) {
    float e = __expf(-2.0f * fabsf(v));
    float r = (1.0f - e) * __builtin_amdgcn_rcpf(1.0f + e);
    return copysignf(r, v);
}

#define PIN4(v) asm volatile("" : "+v"((v).x), "+v"((v).y), "+v"((v).z), "+v"((v).w))
// dot of one float4 weight with one float4 h-slice
#define D4(W, H) ((W).x*(H).x + (W).y*(H).y + (W).z*(H).z + (W).w*(H).w)

// Cross-lane quad reduce WITHOUT the LDS pipe: __shfl_xor lowers to
// ds_bpermute_b32 (LDS hardware); with 72 of them per CU-iteration they
// serialize on the same pipe as the h-broadcast ds_read_b128s (R8-R11's
// ~1080 cyc/iter LDS-pipe load). quad_perm DPP is a pure-VALU permute.
// ctrl 0xB1 = quad_perm [1,0,3,2] (xor 1); 0x4E = [2,3,0,1] (xor 2).
template <int CTRL>
__device__ __forceinline__ float dppadd(float v) {
    int s = __builtin_bit_cast(int, v);
    int p = __builtin_amdgcn_update_dpp(0, s, CTRL, 0xF, 0xF, true);
    return v + __builtin_bit_cast(float, p);
}

// One block per batch, 12 waves. Lane (4g+q) of stage-wave (s,sw) owns
// gate-rows {d, 64+d, 128+d} (d = sw*16+g) x cols [16q,16q+16) = 48 floats
// in named float4 scalars w0..w11. K-quarter partials combine via DPP
// quad_perm adds (VALU, not LDS). ONE barrier per iteration.
//   s=0: h1(i)  = GRU1(h1(i-1), x(i))          [h1b parity]
//   s=1: xg(i-1)= Wih1*h1(i-1)+bih1            [xgb4 parity, packed float4]
//   s=2: h2(i-2)= GRU2(h2(i-3), xg(i-2))       [h2b parity, ring store]
// fc head: wave 7 flushes 64 outputs every 64 iters from the 128-slot ring.
__global__ __launch_bounds__(768, 1)
void gru_fused(const float* __restrict__ x,
               const float* __restrict__ Wih0, const float* __restrict__ Whh0,
               const float* __restrict__ bih0, const float* __restrict__ bhh0,
               const float* __restrict__ Wih1, const float* __restrict__ Whh1,
               const float* __restrict__ bih1, const float* __restrict__ bhh1,
               const float* __restrict__ fcw, const float* __restrict__ fcb,
               float* __restrict__ out)
{
    const int t  = threadIdx.x;
    const int w  = t >> 6;          // wave 0..11
    const int j  = t & 63;          // lane
    const int s  = w >> 2;          // stage 0..2
    const int sw = w & 3;           // dim block
    const int g  = j >> 2;          // local dim 0..15
    const int q  = j & 3;           // K-quarter
    const int d  = sw * 16 + g;     // dim 0..63
    const int b  = blockIdx.x;

    __shared__ __align__(16) float xs[TT * 2];       // 16 KB input
    __shared__ __align__(16) float h1b[2][HH];       // parity
    __shared__ __align__(16) float h2b[2][HH];       // parity
    __shared__ __align__(16) float4 xgb4[2][HH];     // parity, packed {r,z,n,-}
    __shared__ __align__(16) float fwS[HH];
    __shared__ float ring[128][65];                  // h2 history, stride 65

    // ---- 48 weight floats: 3 rows x 16 cols, NAMED scalars ----
    const float* Wm = (s == 0) ? Whh0 : (s == 1) ? Wih1 : Whh1;
    const float4* p0 = (const float4*)(Wm + (size_t)(0 * HH + d) * HH + q * 16);
    const float4* p1 = (const float4*)(Wm + (size_t)(1 * HH + d) * HH + q * 16);
    const float4* p2 = (const float4*)(Wm + (size_t)(2 * HH + d) * HH + q * 16);
    float4 w0 = p0[0], w1 = p0[1], w2  = p0[2], w3  = p0[3];
    float4 w4 = p1[0], w5 = p1[1], w6  = p1[2], w7  = p1[3];
    float4 w8 = p2[0], w9 = p2[1], w10 = p2[2], w11 = p2[3];
    PIN4(w0); PIN4(w1); PIN4(w2);  PIN4(w3);
    PIN4(w4); PIN4(w5); PIN4(w6);  PIN4(w7);
    PIN4(w8); PIN4(w9); PIN4(w10); PIN4(w11);

    // biases (added AFTER the reduce, so loaded once per lane)
    float kb0, kb1, kb2, bi2 = 0.f;
    if (s == 0) {            // r,z: fold bih0+bhh0; n: bhh0 inside r*(), bih0 outside
        kb0 = bhh0[d] + bih0[d];
        kb1 = bhh0[HH + d] + bih0[HH + d];
        kb2 = bhh0[2 * HH + d];
        bi2 = bih0[2 * HH + d];
    } else if (s == 1) {
        kb0 = bih1[d]; kb1 = bih1[HH + d]; kb2 = bih1[2 * HH + d];
    } else {
        kb0 = bhh1[d]; kb1 = bhh1[HH + d]; kb2 = bhh1[2 * HH + d];
    }
    float wi0 = 0, wi1 = 0, wi2 = 0, wi3 = 0, wi4 = 0, wi5 = 0;
    if (s == 0) {
        wi0 = Wih0[d * 2];            wi1 = Wih0[d * 2 + 1];
        wi2 = Wih0[(HH + d) * 2];     wi3 = Wih0[(HH + d) * 2 + 1];
        wi4 = Wih0[(2 * HH + d) * 2]; wi5 = Wih0[(2 * HH + d) * 2 + 1];
    }
    const float fcbv = fcb[0];

    // ---- preload x, zero state ----
    {
        const float4* xp  = (const float4*)(x + (size_t)b * TT * 2);
        float4*       xsp = (float4*)xs;
        for (int i2 = t; i2 < TT * 2 / 4; i2 += 768) xsp[i2] = xp[i2];
    }
    if (t < 2 * HH) { ((float*)h1b)[t] = 0.f; ((float*)h2b)[t] = 0.f; }
    if (t < HH) fwS[t] = fcw[t];

    float hreg = 0.f;   // s0: h1[d]; s2: h2[d] (tracked redundantly by 4 lanes)

    for (int i = 0; i < TT + 2; ++i) {
        __syncthreads();
        const bool act = (s == 0) ? (i < TT)
                       : (s == 1) ? (i >= 1 && i <= TT)
                                  : (i >= 2);
        if (act) {
            const float4* hp = (const float4*)((s < 2) ? h1b[(i - 1) & 1]
                                                       : h2b[(i - 1) & 1]) + q * 4;
            float4 hA = hp[0], hB = hp[1], hC = hp[2], hD = hp[3];
            float a0 = (D4(w0, hA) + D4(w1, hB)) + (D4(w2,  hC) + D4(w3,  hD));
            float a1 = (D4(w4, hA) + D4(w5, hB)) + (D4(w6,  hC) + D4(w7,  hD));
            float a2 = (D4(w8, hA) + D4(w9, hB)) + (D4(w10, hC) + D4(w11, hD));
            // combine K-quarters across lanes 4g..4g+3 via DPP (VALU pipe)
            a0 = dppadd<0xB1>(a0); a0 = dppadd<0x4E>(a0);
            a1 = dppadd<0xB1>(a1); a1 = dppadd<0x4E>(a1);
            a2 = dppadd<0xB1>(a2); a2 = dppadd<0x4E>(a2);
            a0 += kb0; a1 += kb1; a2 += kb2;

            if (s == 0) {                        // layer-1 gates, step i
                float x0 = xs[2 * i], x1 = xs[2 * i + 1];
                float rr = sigm (fmaf(wi0, x0, fmaf(wi1, x1, a0)));
                float zz = sigm (fmaf(wi2, x0, fmaf(wi3, x1, a1)));
                float nn = ftanh(fmaf(wi4, x0, fmaf(wi5, x1, bi2)) + rr * a2);
                hreg = (1.f - zz) * nn + zz * hreg;
                if (q == 0) h1b[i & 1][d] = hreg;
            } else if (s == 1) {                 // xg(i-1) producer, packed
                if (q == 0) xgb4[(i - 1) & 1][d] = make_float4(a0, a1, a2, 0.f);
            } else {                             // layer-2 gates, step i-2
                float4 xg = xgb4[(i - 2) & 1][d];
                float rr = sigm (xg.x + a0);
                float zz = sigm (xg.y + a1);
                float nn = ftanh(xg.z + rr * a2);
                hreg = (1.f - zz) * nn + zz * hreg;
                if (q == 0) {
                    h2b[i & 1][d] = hreg;
                    ring[(i - 2) & 127][d] = hreg;
                }
            }
        }
        // fc-head flush: wave 7, every 64 iters, 64 finished timesteps
        if (w == 7 && i >= 66 && ((i - 66) & 63) == 0) {
            const int tt = ((i - 66) >> 6) * 64 + j;
            const float* rr2 = ring[tt & 127];
            float acc0 = 0.f, acc1 = 0.f;
            #pragma unroll
            for (int k = 0; k < 64; k += 2) {
                acc0 += rr2[k]     * fwS[k];
                acc1 += rr2[k + 1] * fwS[k + 1];
            }
            out[(size_t)b * TT + tt] = acc0 + acc1 + fcbv;
        }
    }
    __syncthreads();
    if (w == 7) {                                // final chunk: t = 1984..2047
        const int tt = 31 * 64 + j;
        const float* rr2 = ring[tt & 127];
        float acc0 = 0.f, acc1 = 0.f;
        #pragma unroll
        for (int k = 0; k < 64; k += 2) {
            acc0 += rr2[k]     * fwS[k];
            acc1 += rr2[k + 1] * fwS[k + 1];
        }
        out[(size_t)b * TT + tt] = acc0 + acc1 + fcbv;
    }
}

extern "C" void kernel_launch(void* const* d_in, const int* in_sizes, int n_in,
                              void* d_out, int out_size, void* d_ws, size_t ws_size,
                              hipStream_t stream) {
    const float* x    = (const float*)d_in[0];
    const float* Wih0 = (const float*)d_in[1];
    const float* Whh0 = (const float*)d_in[2];
    const float* bih0 = (const float*)d_in[3];
    const float* bhh0 = (const float*)d_in[4];
    const float* Wih1 = (const float*)d_in[5];
    const float* Whh1 = (const float*)d_in[6];
    const float* bih1 = (const float*)d_in[7];
    const float* bhh1 = (const float*)d_in[8];
    const float* fcw  = (const float*)d_in[9];
    const float* fcb  = (const float*)d_in[10];
    float* out = (float*)d_out;

    gru_fused<<<BB, 768, 0, stream>>>(x, Wih0, Whh0, bih0, bhh0,
                                      Wih1, Whh1, bih1, bhh1, fcw, fcb, out);
}

// Round 13
// 1379.046 us; speedup vs baseline: 1.1836x; 1.0356x over previous
//
#include <hip/hip_runtime.h>

#define BB 128
#define TT 2048
#define HH 64

__device__ __forceinline__ float sigm(float v) {
    return __builtin_amdgcn_rcpf(1.0f + __expf(-v));
}
__device__ __forceinline__ float ftanh(float v) {
    float e = __expf(-2.0f * fabsf(v));
    float r = (1.0f - e) * __builtin_amdgcn_rcpf(1.0f + e);
    return copysignf(r, v);
}

#define PIN4(v) asm volatile("" : "+v"((v).x), "+v"((v).y), "+v"((v).z), "+v"((v).w))
// dot of one float4 weight with one float4 h-slice
#define D4(W, H) ((W).x*(H).x + (W).y*(H).y + (W).z*(H).z + (W).w*(H).w)

// Cross-lane quad reduce on the VALU pipe (quad_perm DPP), not ds_bpermute.
// ctrl 0xB1 = quad_perm [1,0,3,2] (xor 1); 0x4E = [2,3,0,1] (xor 2).
template <int CTRL>
__device__ __forceinline__ float dppadd(float v) {
    int s = __builtin_bit_cast(int, v);
    int p = __builtin_amdgcn_update_dpp(0, s, CTRL, 0xF, 0xF, true);
    return v + __builtin_bit_cast(float, p);
}

// One block per batch, 12 waves. Lane (4g+q) of stage-wave (s,sw) owns
// gate-rows {d, 64+d, 128+d} (d = sw*16+g) x cols [16q,16q+16) = 48 floats
// in named float4 scalars w0..w11.
//
// R13 CHANGE vs R12: raise the COMPILER'S STATIC OCCUPANCY TARGET so the
// register allocator finally gets a budget > the weight footprint.
// Evidence: R8-R12 all had LDS 52-53KB -> 3 blocks/CU fit -> backend targets
// 9 waves/SIMD -> VGPR cap 512/9 ~= 56 -> granule 48 = the observed
// VGPR_Count every round (weights loop-carried through scratch/L2, the flat
// ~1.5ms). R5 (2 blocks/CU fit -> cap ~102) is the only round that ever
// allocated above it (76, resident). Runtime occupancy is 0.5 block/CU
// (128 blocks / 256 CUs, OccupancyPercent 18), so padding LDS to 86KB
// (ring 128->256 slots) costs NOTHING at runtime but forces the static
// target to 1 block/CU = 3 waves/SIMD -> cap 170. amdgpu_waves_per_eu(3,3)
// pins the same target from the attribute side.
//
// K-quarter partials combine via DPP quad_perm adds. ONE barrier/iter.
//   s=0: h1(i)  = GRU1(h1(i-1), x(i))          [h1b parity]
//   s=1: xg(i-1)= Wih1*h1(i-1)+bih1            [xgb4 parity, packed float4]
//   s=2: h2(i-2)= GRU2(h2(i-3), xg(i-2))       [h2b parity, ring store]
// fc head: wave 7 flushes 64 outputs every 64 iters from the 256-slot ring.
__global__ __launch_bounds__(768)
__attribute__((amdgpu_waves_per_eu(3, 3)))
void gru_fused(const float* __restrict__ x,
               const float* __restrict__ Wih0, const float* __restrict__ Whh0,
               const float* __restrict__ bih0, const float* __restrict__ bhh0,
               const float* __restrict__ Wih1, const float* __restrict__ Whh1,
               const float* __restrict__ bih1, const float* __restrict__ bhh1,
               const float* __restrict__ fcw, const float* __restrict__ fcb,
               float* __restrict__ out)
{
    const int t  = threadIdx.x;
    const int w  = t >> 6;          // wave 0..11
    const int j  = t & 63;          // lane
    const int s  = w >> 2;          // stage 0..2
    const int sw = w & 3;           // dim block
    const int g  = j >> 2;          // local dim 0..15
    const int q  = j & 3;           // K-quarter
    const int d  = sw * 16 + g;     // dim 0..63
    const int b  = blockIdx.x;

    __shared__ __align__(16) float xs[TT * 2];       // 16 KB input
    __shared__ __align__(16) float h1b[2][HH];       // parity
    __shared__ __align__(16) float h2b[2][HH];       // parity
    __shared__ __align__(16) float4 xgb4[2][HH];     // parity, packed {r,z,n,-}
    __shared__ __align__(16) float fwS[HH];
    __shared__ float ring[256][65];                  // h2 history (66.6 KB:
                                                     // pads LDS > 80KB on purpose)

    // ---- 48 weight floats: 3 rows x 16 cols, NAMED scalars ----
    const float* Wm = (s == 0) ? Whh0 : (s == 1) ? Wih1 : Whh1;
    const float4* p0 = (const float4*)(Wm + (size_t)(0 * HH + d) * HH + q * 16);
    const float4* p1 = (const float4*)(Wm + (size_t)(1 * HH + d) * HH + q * 16);
    const float4* p2 = (const float4*)(Wm + (size_t)(2 * HH + d) * HH + q * 16);
    float4 w0 = p0[0], w1 = p0[1], w2  = p0[2], w3  = p0[3];
    float4 w4 = p1[0], w5 = p1[1], w6  = p1[2], w7  = p1[3];
    float4 w8 = p2[0], w9 = p2[1], w10 = p2[2], w11 = p2[3];
    PIN4(w0); PIN4(w1); PIN4(w2);  PIN4(w3);
    PIN4(w4); PIN4(w5); PIN4(w6);  PIN4(w7);
    PIN4(w8); PIN4(w9); PIN4(w10); PIN4(w11);

    // biases (added AFTER the reduce, so loaded once per lane)
    float kb0, kb1, kb2, bi2 = 0.f;
    if (s == 0) {            // r,z: fold bih0+bhh0; n: bhh0 inside r*(), bih0 outside
        kb0 = bhh0[d] + bih0[d];
        kb1 = bhh0[HH + d] + bih0[HH + d];
        kb2 = bhh0[2 * HH + d];
        bi2 = bih0[2 * HH + d];
    } else if (s == 1) {
        kb0 = bih1[d]; kb1 = bih1[HH + d]; kb2 = bih1[2 * HH + d];
    } else {
        kb0 = bhh1[d]; kb1 = bhh1[HH + d]; kb2 = bhh1[2 * HH + d];
    }
    float wi0 = 0, wi1 = 0, wi2 = 0, wi3 = 0, wi4 = 0, wi5 = 0;
    if (s == 0) {
        wi0 = Wih0[d * 2];            wi1 = Wih0[d * 2 + 1];
        wi2 = Wih0[(HH + d) * 2];     wi3 = Wih0[(HH + d) * 2 + 1];
        wi4 = Wih0[(2 * HH + d) * 2]; wi5 = Wih0[(2 * HH + d) * 2 + 1];
    }
    const float fcbv = fcb[0];

    // ---- preload x, zero state ----
    {
        const float4* xp  = (const float4*)(x + (size_t)b * TT * 2);
        float4*       xsp = (float4*)xs;
        for (int i2 = t; i2 < TT * 2 / 4; i2 += 768) xsp[i2] = xp[i2];
    }
    if (t < 2 * HH) { ((float*)h1b)[t] = 0.f; ((float*)h2b)[t] = 0.f; }
    if (t < HH) fwS[t] = fcw[t];

    float hreg = 0.f;   // s0: h1[d]; s2: h2[d] (tracked redundantly by 4 lanes)

    for (int i = 0; i < TT + 2; ++i) {
        __syncthreads();
        const bool act = (s == 0) ? (i < TT)
                       : (s == 1) ? (i >= 1 && i <= TT)
                                  : (i >= 2);
        if (act) {
            const float4* hp = (const float4*)((s < 2) ? h1b[(i - 1) & 1]
                                                       : h2b[(i - 1) & 1]) + q * 4;
            float4 hA = hp[0], hB = hp[1], hC = hp[2], hD = hp[3];
            float a0 = (D4(w0, hA) + D4(w1, hB)) + (D4(w2,  hC) + D4(w3,  hD));
            float a1 = (D4(w4, hA) + D4(w5, hB)) + (D4(w6,  hC) + D4(w7,  hD));
            float a2 = (D4(w8, hA) + D4(w9, hB)) + (D4(w10, hC) + D4(w11, hD));
            // combine K-quarters across lanes 4g..4g+3 via DPP (VALU pipe)
            a0 = dppadd<0xB1>(a0); a0 = dppadd<0x4E>(a0);
            a1 = dppadd<0xB1>(a1); a1 = dppadd<0x4E>(a1);
            a2 = dppadd<0xB1>(a2); a2 = dppadd<0x4E>(a2);
            a0 += kb0; a1 += kb1; a2 += kb2;

            if (s == 0) {                        // layer-1 gates, step i
                float x0 = xs[2 * i], x1 = xs[2 * i + 1];
                float rr = sigm (fmaf(wi0, x0, fmaf(wi1, x1, a0)));
                float zz = sigm (fmaf(wi2, x0, fmaf(wi3, x1, a1)));
                float nn = ftanh(fmaf(wi4, x0, fmaf(wi5, x1, bi2)) + rr * a2);
                hreg = (1.f - zz) * nn + zz * hreg;
                if (q == 0) h1b[i & 1][d] = hreg;
            } else if (s == 1) {                 // xg(i-1) producer, packed
                if (q == 0) xgb4[(i - 1) & 1][d] = make_float4(a0, a1, a2, 0.f);
            } else {                             // layer-2 gates, step i-2
                float4 xg = xgb4[(i - 2) & 1][d];
                float rr = sigm (xg.x + a0);
                float zz = sigm (xg.y + a1);
                float nn = ftanh(xg.z + rr * a2);
                hreg = (1.f - zz) * nn + zz * hreg;
                if (q == 0) {
                    h2b[i & 1][d] = hreg;
                    ring[(i - 2) & 255][d] = hreg;
                }
            }
        }
        // fc-head flush: wave 7, every 64 iters, 64 finished timesteps
        if (w == 7 && i >= 66 && ((i - 66) & 63) == 0) {
            const int tt = ((i - 66) >> 6) * 64 + j;
            const float* rr2 = ring[tt & 255];
            float acc0 = 0.f, acc1 = 0.f;
            #pragma unroll
            for (int k = 0; k < 64; k += 2) {
                acc0 += rr2[k]     * fwS[k];
                acc1 += rr2[k + 1] * fwS[k + 1];
            }
            out[(size_t)b * TT + tt] = acc0 + acc1 + fcbv;
        }
    }
    __syncthreads();
    if (w == 7) {                                // final chunk: t = 1984..2047
        const int tt = 31 * 64 + j;
        const float* rr2 = ring[tt & 255];
        float acc0 = 0.f, acc1 = 0.f;
        #pragma unroll
        for (int k = 0; k < 64; k += 2) {
            acc0 += rr2[k]     * fwS[k];
            acc1 += rr2[k + 1] * fwS[k + 1];
        }
        out[(size_t)b * TT + tt] = acc0 + acc1 + fcbv;
    }
}

extern "C" void kernel_launch(void* const* d_in, const int* in_sizes, int n_in,
                              void* d_out, int out_size, void* d_ws, size_t ws_size,
                              hipStream_t stream) {
    const float* x    = (const float*)d_in[0];
    const float* Wih0 = (const float*)d_in[1];
    const float* Whh0 = (const float*)d_in[2];
    const float* bih0 = (const float*)d_in[3];
    const float* bhh0 = (const float*)d_in[4];
    const float* Wih1 = (const float*)d_in[5];
    const float* Whh1 = (const float*)d_in[6];
    const float* bih1 = (const float*)d_in[7];
    const float* bhh1 = (const float*)d_in[8];
    const float* fcw  = (const float*)d_in[9];
    const float* fcb  = (const float*)d_in[10];
    float* out = (float*)d_out;

    gru_fused<<<BB, 768, 0, stream>>>(x, Wih0, Whh0, bih0, bhh0,
                                      Wih1, Whh1, bih1, bhh1, fcw, fcb, out);
}

// Round 14
// 1324.700 us; speedup vs baseline: 1.2322x; 1.0410x over previous
//
#include <hip/hip_runtime.h>

#define BB 128
#define TT 2048
#define HH 64

typedef float2 f2;

__device__ __forceinline__ float sigm(float v) {
    return __builtin_amdgcn_rcpf(1.0f + __expf(-v));
}
__device__ __forceinline__ float ftanh(float v) {
    float e = __expf(-2.0f * fabsf(v));
    float r = (1.0f - e) * __builtin_amdgcn_rcpf(1.0f + e);
    return copysignf(r, v);
}

#define PIN2(v) asm volatile("" : "+v"(v))
// packed fp32 FMA: acc.lo += w.lo*h.lo, acc.hi += w.hi*h.hi  (VOP3P, 1 inst / 2 MACs)
#define PKFMA(acc, w, h) \
    asm("v_pk_fma_f32 %0, %1, %2, %0" : "+v"(acc) : "v"(w), "v"(h))

// Cross-lane quad reduce on the VALU pipe (quad_perm DPP), not ds_bpermute.
template <int CTRL>
__device__ __forceinline__ float dppadd(float v) {
    int s_ = __builtin_bit_cast(int, v);
    int p_ = __builtin_amdgcn_update_dpp(0, s_, CTRL, 0xF, 0xF, true);
    return v + __builtin_bit_cast(float, p_);
}

// One block per batch, 12 waves (R13 structure, verified). Lane (4g+q) of
// stage-wave (s,sw) owns gate-rows {d,64+d,128+d} x cols [16q,16q+16) = 48
// floats in 24 NAMED float2 (ua/ub/uc 0..7).
//
// R14 CHANGES vs R13 (attack VALU issue, which R13 showed dominates):
//  1. v_pk_fma_f32 dots: 48 scalar FMA -> 24 packed (VOP3P halves dot issue).
//  2. 2x-unrolled time loop: parity indices are compile-time literals,
//     x loaded as one b64, fc-flush test only in even steps.
// Everything else identical: DPP quad-reduce, one barrier/step, LDS pad
// >80KB + waves_per_eu(3,3) for the VGPR budget (R13: first resident round).
__global__ __launch_bounds__(768)
__attribute__((amdgpu_waves_per_eu(3, 3)))
void gru_fused(const float* __restrict__ x,
               const float* __restrict__ Wih0, const float* __restrict__ Whh0,
               const float* __restrict__ bih0, const float* __restrict__ bhh0,
               const float* __restrict__ Wih1, const float* __restrict__ Whh1,
               const float* __restrict__ bih1, const float* __restrict__ bhh1,
               const float* __restrict__ fcw, const float* __restrict__ fcb,
               float* __restrict__ out)
{
    const int t  = threadIdx.x;
    const int w  = t >> 6;          // wave 0..11
    const int j  = t & 63;          // lane
    const int s  = w >> 2;          // stage 0..2
    const int sw = w & 3;           // dim block
    const int g  = j >> 2;          // local dim 0..15
    const int q  = j & 3;           // K-quarter
    const int d  = sw * 16 + g;     // dim 0..63
    const int b  = blockIdx.x;

    __shared__ __align__(16) float xs[TT * 2];       // 16 KB input
    __shared__ __align__(16) float h1b[2][HH];       // parity
    __shared__ __align__(16) float h2b[2][HH];       // parity
    __shared__ __align__(16) float4 xgb4[2][HH];     // parity, packed {r,z,n,-}
    __shared__ __align__(16) float fwS[HH];
    __shared__ float ring[256][65];                  // h2 history (pads LDS >80KB
                                                     // on purpose: 1-block/CU target)

    // ---- 48 weight floats as 24 named float2 ----
    const float* Wm = (s == 0) ? Whh0 : (s == 1) ? Wih1 : Whh1;
    const float4* p0 = (const float4*)(Wm + (size_t)(0 * HH + d) * HH + q * 16);
    const float4* p1 = (const float4*)(Wm + (size_t)(1 * HH + d) * HH + q * 16);
    const float4* p2 = (const float4*)(Wm + (size_t)(2 * HH + d) * HH + q * 16);
    float4 A0 = p0[0], A1 = p0[1], A2 = p0[2], A3 = p0[3];
    float4 B0 = p1[0], B1 = p1[1], B2 = p1[2], B3 = p1[3];
    float4 C0 = p2[0], C1 = p2[1], C2 = p2[2], C3 = p2[3];
    f2 ua0 = {A0.x, A0.y}, ua1 = {A0.z, A0.w}, ua2 = {A1.x, A1.y}, ua3 = {A1.z, A1.w};
    f2 ua4 = {A2.x, A2.y}, ua5 = {A2.z, A2.w}, ua6 = {A3.x, A3.y}, ua7 = {A3.z, A3.w};
    f2 ub0 = {B0.x, B0.y}, ub1 = {B0.z, B0.w}, ub2 = {B1.x, B1.y}, ub3 = {B1.z, B1.w};
    f2 ub4 = {B2.x, B2.y}, ub5 = {B2.z, B2.w}, ub6 = {B3.x, B3.y}, ub7 = {B3.z, B3.w};
    f2 uc0 = {C0.x, C0.y}, uc1 = {C0.z, C0.w}, uc2 = {C1.x, C1.y}, uc3 = {C1.z, C1.w};
    f2 uc4 = {C2.x, C2.y}, uc5 = {C2.z, C2.w}, uc6 = {C3.x, C3.y}, uc7 = {C3.z, C3.w};
    PIN2(ua0); PIN2(ua1); PIN2(ua2); PIN2(ua3);
    PIN2(ua4); PIN2(ua5); PIN2(ua6); PIN2(ua7);
    PIN2(ub0); PIN2(ub1); PIN2(ub2); PIN2(ub3);
    PIN2(ub4); PIN2(ub5); PIN2(ub6); PIN2(ub7);
    PIN2(uc0); PIN2(uc1); PIN2(uc2); PIN2(uc3);
    PIN2(uc4); PIN2(uc5); PIN2(uc6); PIN2(uc7);

    // biases (added AFTER the reduce, so loaded once per lane)
    float kb0, kb1, kb2, bi2 = 0.f;
    if (s == 0) {            // r,z: fold bih0+bhh0; n: bhh0 inside r*(), bih0 outside
        kb0 = bhh0[d] + bih0[d];
        kb1 = bhh0[HH + d] + bih0[HH + d];
        kb2 = bhh0[2 * HH + d];
        bi2 = bih0[2 * HH + d];
    } else if (s == 1) {
        kb0 = bih1[d]; kb1 = bih1[HH + d]; kb2 = bih1[2 * HH + d];
    } else {
        kb0 = bhh1[d]; kb1 = bhh1[HH + d]; kb2 = bhh1[2 * HH + d];
    }
    float wi0 = 0, wi1 = 0, wi2 = 0, wi3 = 0, wi4 = 0, wi5 = 0;
    if (s == 0) {
        wi0 = Wih0[d * 2];            wi1 = Wih0[d * 2 + 1];
        wi2 = Wih0[(HH + d) * 2];     wi3 = Wih0[(HH + d) * 2 + 1];
        wi4 = Wih0[(2 * HH + d) * 2]; wi5 = Wih0[(2 * HH + d) * 2 + 1];
    }
    const float fcbv = fcb[0];

    // ---- preload x, zero state ----
    {
        const float4* xp  = (const float4*)(x + (size_t)b * TT * 2);
        float4*       xsp = (float4*)xs;
        for (int i2 = t; i2 < TT * 2 / 4; i2 += 768) xsp[i2] = xp[i2];
    }
    if (t < 2 * HH) { ((float*)h1b)[t] = 0.f; ((float*)h2b)[t] = 0.f; }
    if (t < HH) fwS[t] = fcw[t];

    float hreg = 0.f;   // s0: h1[d]; s2: h2[d] (tracked redundantly by 4 lanes)

// One timestep. PC = IDX&1, PP = (IDX-1)&1 as literals; FL = fc-flush test
// (flush steps satisfy i ≡ 2 (mod 64), i.e. even, so only the PC==0 copy).
#define STEP(IDX, PC, PP, FL)                                                  \
    {                                                                          \
        __syncthreads();                                                       \
        const int i_ = (IDX);                                                  \
        const bool act = (s == 0) ? (i_ < TT)                                  \
                       : (s == 1) ? (i_ >= 1 && i_ <= TT)                      \
                                  : (i_ >= 2);                                 \
        if (act) {                                                             \
            const float4* hp = (const float4*)((s < 2) ? h1b[PP] : h2b[PP]) + q * 4; \
            float4 zA = hp[0], zB = hp[1], zC = hp[2], zD = hp[3];             \
            f2 z0 = {zA.x, zA.y}, z1 = {zA.z, zA.w};                           \
            f2 z2 = {zB.x, zB.y}, z3 = {zB.z, zB.w};                           \
            f2 z4 = {zC.x, zC.y}, z5 = {zC.z, zC.w};                           \
            f2 z6 = {zD.x, zD.y}, z7 = {zD.z, zD.w};                           \
            f2 ac0 = {0.f, 0.f}, ac1 = {0.f, 0.f}, ac2 = {0.f, 0.f};           \
            PKFMA(ac0, ua0, z0); PKFMA(ac1, ub0, z0); PKFMA(ac2, uc0, z0);     \
            PKFMA(ac0, ua1, z1); PKFMA(ac1, ub1, z1); PKFMA(ac2, uc1, z1);     \
            PKFMA(ac0, ua2, z2); PKFMA(ac1, ub2, z2); PKFMA(ac2, uc2, z2);     \
            PKFMA(ac0, ua3, z3); PKFMA(ac1, ub3, z3); PKFMA(ac2, uc3, z3);     \
            PKFMA(ac0, ua4, z4); PKFMA(ac1, ub4, z4); PKFMA(ac2, uc4, z4);     \
            PKFMA(ac0, ua5, z5); PKFMA(ac1, ub5, z5); PKFMA(ac2, uc5, z5);     \
            PKFMA(ac0, ua6, z6); PKFMA(ac1, ub6, z6); PKFMA(ac2, uc6, z6);     \
            PKFMA(ac0, ua7, z7); PKFMA(ac1, ub7, z7); PKFMA(ac2, uc7, z7);     \
            float a0 = ac0.x + ac0.y, a1 = ac1.x + ac1.y, a2 = ac2.x + ac2.y;  \
            a0 = dppadd<0xB1>(a0); a0 = dppadd<0x4E>(a0);                      \
            a1 = dppadd<0xB1>(a1); a1 = dppadd<0x4E>(a1);                      \
            a2 = dppadd<0xB1>(a2); a2 = dppadd<0x4E>(a2);                      \
            a0 += kb0; a1 += kb1; a2 += kb2;                                   \
            if (s == 0) {                                                      \
                f2 xv = *(const f2*)(xs + 2 * i_);                             \
                float rr = sigm (fmaf(wi0, xv.x, fmaf(wi1, xv.y, a0)));        \
                float zz = sigm (fmaf(wi2, xv.x, fmaf(wi3, xv.y, a1)));        \
                float nn = ftanh(fmaf(wi4, xv.x, fmaf(wi5, xv.y, bi2)) + rr * a2); \
                hreg = (1.f - zz) * nn + zz * hreg;                            \
                if (q == 0) h1b[PC][d] = hreg;                                 \
            } else if (s == 1) {                                               \
                if (q == 0) xgb4[PP][d] = make_float4(a0, a1, a2, 0.f);        \
            } else {                                                           \
                float4 xg = xgb4[PC][d];                                       \
                float rr = sigm (xg.x + a0);                                   \
                float zz = sigm (xg.y + a1);                                   \
                float nn = ftanh(xg.z + rr * a2);                              \
                hreg = (1.f - zz) * nn + zz * hreg;                            \
                if (q == 0) {                                                  \
                    h2b[PC][d] = hreg;                                         \
                    ring[(i_ - 2) & 255][d] = hreg;                            \
                }                                                              \
            }                                                                  \
        }                                                                      \
        if (FL && w == 7 && i_ >= 66 && ((i_ - 66) & 63) == 0) {               \
            const int tt = ((i_ - 66) >> 6) * 64 + j;                          \
            const float* rr2 = ring[tt & 255];                                 \
            float acc0 = 0.f, acc1 = 0.f;                                      \
            _Pragma("unroll")                                                  \
            for (int k = 0; k < 64; k += 2) {                                  \
                acc0 += rr2[k]     * fwS[k];                                   \
                acc1 += rr2[k + 1] * fwS[k + 1];                               \
            }                                                                  \
            out[(size_t)b * TT + tt] = acc0 + acc1 + fcbv;                     \
        }                                                                      \
    }

    for (int ii = 0; ii < TT + 2; ii += 2) {
        STEP(ii,     0, 1, true);     // even step: parity (0,1), flush check
        STEP(ii + 1, 1, 0, false);    // odd  step: parity (1,0)
    }
#undef STEP

    __syncthreads();
    if (w == 7) {                                // final chunk: t = 1984..2047
        const int tt = 31 * 64 + j;
        const float* rr2 = ring[tt & 255];
        float acc0 = 0.f, acc1 = 0.f;
        #pragma unroll
        for (int k = 0; k < 64; k += 2) {
            acc0 += rr2[k]     * fwS[k];
            acc1 += rr2[k + 1] * fwS[k + 1];
        }
        out[(size_t)b * TT + tt] = acc0 + acc1 + fcbv;
    }
}

extern "C" void kernel_launch(void* const* d_in, const int* in_sizes, int n_in,
                              void* d_out, int out_size, void* d_ws, size_t ws_size,
                              hipStream_t stream) {
    const float* x    = (const float*)d_in[0];
    const float* Wih0 = (const float*)d_in[1];
    const float* Whh0 = (const float*)d_in[2];
    const float* bih0 = (const float*)d_in[3];
    const float* bhh0 = (const float*)d_in[4];
    const float* Wih1 = (const float*)d_in[5];
    const float* Whh1 = (const float*)d_in[6];
    const float* bih1 = (const float*)d_in[7];
    const float* bhh1 = (const float*)d_in[8];
    const float* fcw  = (const float*)d_in[9];
    const float* fcb  = (const float*)d_in[10];
    float* out = (float*)d_out;

    gru_fused<<<BB, 768, 0, stream>>>(x, Wih0, Whh0, bih0, bhh0,
                                      Wih1, Whh1, bih1, bhh1, fcw, fcb, out);
}

// Round 15
// 993.804 us; speedup vs baseline: 1.6425x; 1.3330x over previous
//
#include <hip/hip_runtime.h>

#define BB 128
#define TT 2048
#define HH 64

typedef float2 f2;
struct f2x2 { f2 lo, hi; };

__device__ __forceinline__ float sigm(float v) {
    return __builtin_amdgcn_rcpf(1.0f + __expf(-v));
}
__device__ __forceinline__ float ftanh(float v) {
    float e = __expf(-2.0f * fabsf(v));
    float r = (1.0f - e) * __builtin_amdgcn_rcpf(1.0f + e);
    return copysignf(r, v);
}

#define PIN2(v) asm volatile("" : "+v"(v))
// packed fp32 FMA: 1 inst / 2 MACs (VOP3P)
#define PKFMA(acc, w, h) \
    asm("v_pk_fma_f32 %0, %1, %2, %0" : "+v"(acc) : "v"(w), "v"(h))
// split a float4 (4 consecutive VGPRs) into two f2 register pairs, no movs
#define SPLIT(v4, lo_, hi_) \
    { f2x2 u_ = __builtin_bit_cast(f2x2, (v4)); lo_ = u_.lo; hi_ = u_.hi; }

// + lane^1 via quad_perm DPP (VALU pipe, not LDS)
__device__ __forceinline__ float dppadd1(float v) {
    int s_ = __builtin_bit_cast(int, v);
    int p_ = __builtin_amdgcn_update_dpp(0, s_, 0xB1, 0xF, 0xF, true);
    return v + __builtin_bit_cast(float, p_);
}

// One block per batch, SIX waves (R15: halve wave count vs R14's 12 to halve
// replicated per-wave overhead; work is invariant at 288 pk_fma/CU-iter).
// Lane (2g+q) of stage-wave (s,sw) owns gate-rows {d,64+d,128+d}
// (d = sw*32+g) x cols [32q,32q+32) = 96 floats in 48 NAMED f2.
// Residency mechanism (R13-proven): LDS pad >80KB -> 1 block/CU static
// occupancy target; 6 waves -> 2 waves/EU -> VGPR cap ~256 >> ~160 needed.
// K-half partials combine with ONE dppadd (xor 1). Gate redundancy 2x.
// Wave->stage map interleaves heavy/light on SIMDs (wave i -> SIMD i%4):
//   w0(s0,h0) w1(s2,h0) w2(s0,h1) w3(s2,h1) w4(s1,h0) w5(s1,h1)
//   s=0: h1(i)  = GRU1(h1(i-1), x(i))          [h1b parity]
//   s=1: xg(i-1)= Wih1*h1(i-1)+bih1            [xgb4 parity, packed float4]
//   s=2: h2(i-2)= GRU2(h2(i-3), xg(i-2))       [h2b parity, ring store]
// fc head: wave 3 flushes 64 outputs every 64 iters from the 256-slot ring.
__global__ __launch_bounds__(384)
__attribute__((amdgpu_waves_per_eu(1, 2)))
void gru_fused(const float* __restrict__ x,
               const float* __restrict__ Wih0, const float* __restrict__ Whh0,
               const float* __restrict__ bih0, const float* __restrict__ bhh0,
               const float* __restrict__ Wih1, const float* __restrict__ Whh1,
               const float* __restrict__ bih1, const float* __restrict__ bhh1,
               const float* __restrict__ fcw, const float* __restrict__ fcb,
               float* __restrict__ out)
{
    const int t  = threadIdx.x;
    const int w  = t >> 6;          // wave 0..5
    const int j  = t & 63;          // lane
    const int s  = (w < 4) ? ((w & 1) ? 2 : 0) : 1;   // stage
    const int sw = (w < 4) ? (w >> 1) : (w & 1);      // dim half
    const int g  = j >> 1;          // local dim 0..31
    const int q  = j & 1;           // K-half
    const int d  = sw * 32 + g;     // dim 0..63
    const int b  = blockIdx.x;

    __shared__ __align__(16) float xs[TT * 2];       // 16 KB input
    __shared__ __align__(16) float h1b[2][HH];       // parity
    __shared__ __align__(16) float h2b[2][HH];       // parity
    __shared__ __align__(16) float4 xgb4[2][HH];     // parity, packed {r,z,n,-}
    __shared__ __align__(16) float fwS[HH];
    __shared__ float ring[256][65];                  // h2 history (pads LDS >80KB
                                                     // on purpose: 1-block/CU target)

    // ---- 96 weight floats as 48 named f2 (3 rows x 32 cols) ----
    const float* Wm = (s == 0) ? Whh0 : (s == 1) ? Wih1 : Whh1;
    const float4* P0 = (const float4*)(Wm + (size_t)(0 * HH + d) * HH + q * 32);
    const float4* P1 = (const float4*)(Wm + (size_t)(1 * HH + d) * HH + q * 32);
    const float4* P2 = (const float4*)(Wm + (size_t)(2 * HH + d) * HH + q * 32);
    f2 wa0, wa1, wa2, wa3, wa4, wa5, wa6, wa7,
       wa8, wa9, wa10, wa11, wa12, wa13, wa14, wa15;
    f2 wb0, wb1, wb2, wb3, wb4, wb5, wb6, wb7,
       wb8, wb9, wb10, wb11, wb12, wb13, wb14, wb15;
    f2 wc0, wc1, wc2, wc3, wc4, wc5, wc6, wc7,
       wc8, wc9, wc10, wc11, wc12, wc13, wc14, wc15;
    {
        float4 v;
        v = P0[0]; SPLIT(v, wa0,  wa1);  v = P0[1]; SPLIT(v, wa2,  wa3);
        v = P0[2]; SPLIT(v, wa4,  wa5);  v = P0[3]; SPLIT(v, wa6,  wa7);
        v = P0[4]; SPLIT(v, wa8,  wa9);  v = P0[5]; SPLIT(v, wa10, wa11);
        v = P0[6]; SPLIT(v, wa12, wa13); v = P0[7]; SPLIT(v, wa14, wa15);
        v = P1[0]; SPLIT(v, wb0,  wb1);  v = P1[1]; SPLIT(v, wb2,  wb3);
        v = P1[2]; SPLIT(v, wb4,  wb5);  v = P1[3]; SPLIT(v, wb6,  wb7);
        v = P1[4]; SPLIT(v, wb8,  wb9);  v = P1[5]; SPLIT(v, wb10, wb11);
        v = P1[6]; SPLIT(v, wb12, wb13); v = P1[7]; SPLIT(v, wb14, wb15);
        v = P2[0]; SPLIT(v, wc0,  wc1);  v = P2[1]; SPLIT(v, wc2,  wc3);
        v = P2[2]; SPLIT(v, wc4,  wc5);  v = P2[3]; SPLIT(v, wc6,  wc7);
        v = P2[4]; SPLIT(v, wc8,  wc9);  v = P2[5]; SPLIT(v, wc10, wc11);
        v = P2[6]; SPLIT(v, wc12, wc13); v = P2[7]; SPLIT(v, wc14, wc15);
    }
    PIN2(wa0);  PIN2(wa1);  PIN2(wa2);  PIN2(wa3);
    PIN2(wa4);  PIN2(wa5);  PIN2(wa6);  PIN2(wa7);
    PIN2(wa8);  PIN2(wa9);  PIN2(wa10); PIN2(wa11);
    PIN2(wa12); PIN2(wa13); PIN2(wa14); PIN2(wa15);
    PIN2(wb0);  PIN2(wb1);  PIN2(wb2);  PIN2(wb3);
    PIN2(wb4);  PIN2(wb5);  PIN2(wb6);  PIN2(wb7);
    PIN2(wb8);  PIN2(wb9);  PIN2(wb10); PIN2(wb11);
    PIN2(wb12); PIN2(wb13); PIN2(wb14); PIN2(wb15);
    PIN2(wc0);  PIN2(wc1);  PIN2(wc2);  PIN2(wc3);
    PIN2(wc4);  PIN2(wc5);  PIN2(wc6);  PIN2(wc7);
    PIN2(wc8);  PIN2(wc9);  PIN2(wc10); PIN2(wc11);
    PIN2(wc12); PIN2(wc13); PIN2(wc14); PIN2(wc15);

    // biases (added AFTER the reduce, so loaded once per lane)
    float kb0, kb1, kb2, bi2 = 0.f;
    if (s == 0) {            // r,z: fold bih0+bhh0; n: bhh0 inside r*(), bih0 outside
        kb0 = bhh0[d] + bih0[d];
        kb1 = bhh0[HH + d] + bih0[HH + d];
        kb2 = bhh0[2 * HH + d];
        bi2 = bih0[2 * HH + d];
    } else if (s == 1) {
        kb0 = bih1[d]; kb1 = bih1[HH + d]; kb2 = bih1[2 * HH + d];
    } else {
        kb0 = bhh1[d]; kb1 = bhh1[HH + d]; kb2 = bhh1[2 * HH + d];
    }
    float wi0 = 0, wi1 = 0, wi2 = 0, wi3 = 0, wi4 = 0, wi5 = 0;
    if (s == 0) {
        wi0 = Wih0[d * 2];            wi1 = Wih0[d * 2 + 1];
        wi2 = Wih0[(HH + d) * 2];     wi3 = Wih0[(HH + d) * 2 + 1];
        wi4 = Wih0[(2 * HH + d) * 2]; wi5 = Wih0[(2 * HH + d) * 2 + 1];
    }
    const float fcbv = fcb[0];

    // ---- preload x, zero state ----
    {
        const float4* xp  = (const float4*)(x + (size_t)b * TT * 2);
        float4*       xsp = (float4*)xs;
        for (int i2 = t; i2 < TT * 2 / 4; i2 += 384) xsp[i2] = xp[i2];
    }
    if (t < 2 * HH) { ((float*)h1b)[t] = 0.f; ((float*)h2b)[t] = 0.f; }
    if (t < HH) fwS[t] = fcw[t];

    float hreg = 0.f;   // s0: h1[d]; s2: h2[d] (tracked redundantly by 2 lanes)

// One timestep. PC = IDX&1, PP = (IDX-1)&1 as literals; FL = fc-flush test
// (flush steps are even, so only the PC==0 copy checks).
#define STEP(IDX, PC, PP, FL)                                                  \
    {                                                                          \
        __syncthreads();                                                       \
        const int i_ = (IDX);                                                  \
        const bool act = (s == 0) ? (i_ < TT)                                  \
                       : (s == 1) ? (i_ >= 1 && i_ <= TT)                      \
                                  : (i_ >= 2);                                 \
        if (act) {                                                             \
            const float4* hp = ((const float4*)((s < 2) ? h1b[PP] : h2b[PP])) + q * 8; \
            f2 h0, h1, h2, h3, h4, h5, h6, h7,                                 \
               h8, h9, h10, h11, h12, h13, h14, h15;                           \
            {                                                                  \
                float4 v_;                                                     \
                v_ = hp[0]; SPLIT(v_, h0,  h1);  v_ = hp[1]; SPLIT(v_, h2,  h3); \
                v_ = hp[2]; SPLIT(v_, h4,  h5);  v_ = hp[3]; SPLIT(v_, h6,  h7); \
                v_ = hp[4]; SPLIT(v_, h8,  h9);  v_ = hp[5]; SPLIT(v_, h10, h11);\
                v_ = hp[6]; SPLIT(v_, h12, h13); v_ = hp[7]; SPLIT(v_, h14, h15);\
            }                                                                  \
            f2 aR = {0.f, 0.f}, aZ = {0.f, 0.f}, aN = {0.f, 0.f};              \
            PKFMA(aR, wa0,  h0);  PKFMA(aZ, wb0,  h0);  PKFMA(aN, wc0,  h0);   \
            PKFMA(aR, wa1,  h1);  PKFMA(aZ, wb1,  h1);  PKFMA(aN, wc1,  h1);   \
            PKFMA(aR, wa2,  h2);  PKFMA(aZ, wb2,  h2);  PKFMA(aN, wc2,  h2);   \
            PKFMA(aR, wa3,  h3);  PKFMA(aZ, wb3,  h3);  PKFMA(aN, wc3,  h3);   \
            PKFMA(aR, wa4,  h4);  PKFMA(aZ, wb4,  h4);  PKFMA(aN, wc4,  h4);   \
            PKFMA(aR, wa5,  h5);  PKFMA(aZ, wb5,  h5);  PKFMA(aN, wc5,  h5);   \
            PKFMA(aR, wa6,  h6);  PKFMA(aZ, wb6,  h6);  PKFMA(aN, wc6,  h6);   \
            PKFMA(aR, wa7,  h7);  PKFMA(aZ, wb7,  h7);  PKFMA(aN, wc7,  h7);   \
            PKFMA(aR, wa8,  h8);  PKFMA(aZ, wb8,  h8);  PKFMA(aN, wc8,  h8);   \
            PKFMA(aR, wa9,  h9);  PKFMA(aZ, wb9,  h9);  PKFMA(aN, wc9,  h9);   \
            PKFMA(aR, wa10, h10); PKFMA(aZ, wb10, h10); PKFMA(aN, wc10, h10);  \
            PKFMA(aR, wa11, h11); PKFMA(aZ, wb11, h11); PKFMA(aN, wc11, h11);  \
            PKFMA(aR, wa12, h12); PKFMA(aZ, wb12, h12); PKFMA(aN, wc12, h12);  \
            PKFMA(aR, wa13, h13); PKFMA(aZ, wb13, h13); PKFMA(aN, wc13, h13);  \
            PKFMA(aR, wa14, h14); PKFMA(aZ, wb14, h14); PKFMA(aN, wc14, h14);  \
            PKFMA(aR, wa15, h15); PKFMA(aZ, wb15, h15); PKFMA(aN, wc15, h15);  \
            float sr = aR.x + aR.y, sz = aZ.x + aZ.y, sn = aN.x + aN.y;        \
            sr = dppadd1(sr); sz = dppadd1(sz); sn = dppadd1(sn);              \
            sr += kb0; sz += kb1; sn += kb2;                                   \
            if (s == 0) {                                                      \
                f2 xv = *(const f2*)(xs + 2 * i_);                             \
                float rr = sigm (fmaf(wi0, xv.x, fmaf(wi1, xv.y, sr)));        \
                float zz = sigm (fmaf(wi2, xv.x, fmaf(wi3, xv.y, sz)));        \
                float nn = ftanh(fmaf(wi4, xv.x, fmaf(wi5, xv.y, bi2)) + rr * sn); \
                hreg = (1.f - zz) * nn + zz * hreg;                            \
                if (q == 0) h1b[PC][d] = hreg;                                 \
            } else if (s == 1) {                                               \
                if (q == 0) xgb4[PP][d] = make_float4(sr, sz, sn, 0.f);        \
            } else {                                                           \
                float4 xg = xgb4[PC][d];                                       \
                float rr = sigm (xg.x + sr);                                   \
                float zz = sigm (xg.y + sz);                                   \
                float nn = ftanh(xg.z + rr * sn);                              \
                hreg = (1.f - zz) * nn + zz * hreg;                            \
                if (q == 0) {                                                  \
                    h2b[PC][d] = hreg;                                         \
                    ring[(i_ - 2) & 255][d] = hreg;                            \
                }                                                              \
            }                                                                  \
        }                                                                      \
        if (FL && w == 3 && i_ >= 66 && ((i_ - 66) & 63) == 0) {               \
            const int tt = ((i_ - 66) >> 6) * 64 + j;                          \
            const float* rr2 = ring[tt & 255];                                 \
            float acc0 = 0.f, acc1 = 0.f;                                      \
            _Pragma("unroll")                                                  \
            for (int k = 0; k < 64; k += 2) {                                  \
                acc0 += rr2[k]     * fwS[k];                                   \
                acc1 += rr2[k + 1] * fwS[k + 1];                               \
            }                                                                  \
            out[(size_t)b * TT + tt] = acc0 + acc1 + fcbv;                     \
        }                                                                      \
    }

    for (int ii = 0; ii < TT + 2; ii += 2) {
        STEP(ii,     0, 1, true);     // even step: parity (0,1), flush check
        STEP(ii + 1, 1, 0, false);    // odd  step: parity (1,0)
    }
#undef STEP

    __syncthreads();
    if (w == 3) {                                // final chunk: t = 1984..2047
        const int tt = 31 * 64 + j;
        const float* rr2 = ring[tt & 255];
        float acc0 = 0.f, acc1 = 0.f;
        #pragma unroll
        for (int k = 0; k < 64; k += 2) {
            acc0 += rr2[k]     * fwS[k];
            acc1 += rr2[k + 1] * fwS[k + 1];
        }
        out[(size_t)b * TT + tt] = acc0 + acc1 + fcbv;
    }
}

extern "C" void kernel_launch(void* const* d_in, const int* in_sizes, int n_in,
                              void* d_out, int out_size, void* d_ws, size_t ws_size,
                              hipStream_t stream) {
    const float* x    = (const float*)d_in[0];
    const float* Wih0 = (const float*)d_in[1];
    const float* Whh0 = (const float*)d_in[2];
    const float* bih0 = (const float*)d_in[3];
    const float* bhh0 = (const float*)d_in[4];
    const float* Wih1 = (const float*)d_in[5];
    const float* Whh1 = (const float*)d_in[6];
    const float* bih1 = (const float*)d_in[7];
    const float* bhh1 = (const float*)d_in[8];
    const float* fcw  = (const float*)d_in[9];
    const float* fcb  = (const float*)d_in[10];
    float* out = (float*)d_out;

    gru_fused<<<BB, 384, 0, stream>>>(x, Wih0, Whh0, bih0, bhh0,
                                      Wih1, Whh1, bih1, bhh1, fcw, fcb, out);
}